// Round 6
// baseline (534.998 us; speedup 1.0000x reference)
//
#include <hip/hip_runtime.h>

typedef unsigned int u32;
typedef unsigned short u16;
typedef __attribute__((ext_vector_type(8))) short s16x8;
typedef __attribute__((ext_vector_type(4))) float f32x4;
typedef float f32x4a __attribute__((ext_vector_type(4), aligned(8)));  // 8B-aligned 16B load
typedef u32  u32x2a  __attribute__((ext_vector_type(2), aligned(4)));  // 4B-aligned 8B load

#define TBL    524288u
#define TMASK  (TBL - 1u)
#define HPRIME 2654435761u
#define NBINS  65536

// res[l] = floor(16 * 1.3819^l); dense (linear) while (res+1)^2 <= 2^19 -> levels 0..11
__device__ constexpr int RESI[16] = {16,22,30,42,58,80,111,153,212,294,406,561,775,1072,1481,2047};

static __device__ __forceinline__ u16 f2bf(float f){            // RNE f32->bf16 (manual)
  u32 u = __builtin_bit_cast(u32, f);
  return (u16)((u + 0x7fffu + ((u >> 16) & 1u)) >> 16);
}
static __device__ __forceinline__ float bf2f(u16 h){ return __builtin_bit_cast(float, (u32)h << 16); }
static __device__ __forceinline__ float blo(u32 e){ return __builtin_bit_cast(float, (u32)(e << 16)); }
static __device__ __forceinline__ float bhi(u32 e){ return __builtin_bit_cast(float, (u32)(e & 0xffff0000u)); }
static __device__ __forceinline__ u32 packbf2(float a, float b){ return (u32)f2bf(a) | ((u32)f2bf(b) << 16); }
// HW packed RNE f32->bf16 (gfx950): D.lo = bf16(a), D.hi = bf16(b). Same rounding as f2bf.
static __device__ __forceinline__ u32 cvtpk(float a, float b){
  u32 r; asm("v_cvt_pk_bf16_f32 %0, %1, %2" : "=v"(r) : "v"(a), "v"(b)); return r;
}
// 8-bit Morton spread
static __device__ __forceinline__ u32 spread8(u32 v){
  v &= 0xFFu;
  v = (v | (v << 4)) & 0x0F0Fu;
  v = (v | (v << 2)) & 0x3333u;
  v = (v | (v << 1)) & 0x5555u;
  return v;
}
static __device__ __forceinline__ u32 mkey(float x, float y){
  u32 kx = (u32)(x * 256.f); kx = kx > 255u ? 255u : kx;
  u32 ky = (u32)(y * 256.f); ky = ky > 255u ? 255u : ky;
  return spread8(kx) | (spread8(ky) << 1);
}

#define MFMA(A,B,C) __builtin_amdgcn_mfma_f32_16x16x32_bf16((A),(B),(C),0,0,0)

// R6 pre-pass: fp32 tables (64 MB) -> packed-bf16 tables (32 MB) in d_ws.
__global__ __launch_bounds__(256) void cvt_tab(const float4* __restrict__ src,
                                               uint2* __restrict__ dst, int n4) {
  for (int i = blockIdx.x*256 + threadIdx.x; i < n4; i += gridDim.x*256) {
    const float4 v = src[i];
    dst[i] = make_uint2(packbf2(v.x, v.y), packbf2(v.z, v.w));
  }
}

// R12 sort pre-passes: input points are RANDOM order -> every phase-A gather is fully
// scattered. Morton counting-sort (64K bins ~ 1/256 cells) makes a wave's 64 points
// spatially adjacent -> gathers share cache lines. Per-point math is order-independent,
// so results are bit-identical; out is written through perm.
__global__ __launch_bounds__(256) void hist_k(const float2* __restrict__ xq,
                                              u32* __restrict__ hist, int n) {
  for (int i = blockIdx.x*256 + threadIdx.x; i < n; i += gridDim.x*256) {
    const float2 p = xq[i];
    atomicAdd(&hist[mkey(p.x, p.y)], 1u);
  }
}
// in-place exclusive scan of 65536 bins (1024 threads x 64 bins)
__global__ __launch_bounds__(1024) void scan_k(u32* __restrict__ hist) {
  __shared__ u32 part[1024];
  const int t = threadIdx.x;
  u32 s = 0;
  for (int i = 0; i < 64; ++i) s += hist[t*64 + i];
  part[t] = s;
  __syncthreads();
  for (int d = 1; d < 1024; d <<= 1) {
    const u32 v = (t >= d) ? part[t - d] : 0u;
    __syncthreads();
    part[t] += v;
    __syncthreads();
  }
  u32 run = part[t] - s;                 // exclusive prefix of this chunk
  for (int i = 0; i < 64; ++i) {
    const u32 h = hist[t*64 + i];        // read before overwrite (same thread)
    hist[t*64 + i] = run;
    run += h;
  }
}
__global__ __launch_bounds__(256) void scat_k(const float2* __restrict__ xq,
                                              u32* __restrict__ offs,
                                              float2* __restrict__ xs,
                                              u32* __restrict__ perm, int n) {
  for (int i = blockIdx.x*256 + threadIdx.x; i < n; i += gridDim.x*256) {
    const float2 p = xq[i];
    const u32 pos = atomicAdd(&offs[mkey(p.x, p.y)], 1u);
    xs[pos] = p;
    perm[pos] = (u32)i;
  }
}

// Fused instant-NGP: fp32 hash-grid encode (per-thread) + 34->64->64->3 MLP via bf16-split MFMA.
// OCCUPANCY MODEL (verified R8/R9/R10): 3 blocks/CU iff arch VGPR <= ~104 AND LDS <= 53248 B.
// Budget now: VGPR ~90/104, LDS 51200/53248. DO NOT grow either.
// History: 515(R2)->443(R5)->392(R6 packed)->375(R8 evict)->363(R10 cvt_pk+planes,3blk/CU)
// ->336(R11 hash-first). R3/R4/R9 squeezes: spills. R7 LDS-prefetch: dead end.
// R12: (a) plane stride 80->72 u16: R11's XOR swizzle was a no-op (conflicts 17.3M exactly
// unchanged - 4-row group stride was ==0 mod 128B so q never reached the bank bits; XOR
// q<<3 only permuted within a 16-col block). Stride 72: write bank = 16q+4r+8c+m/2 -> 2
// dwords/bank ~ free. (b) Morton sort (see sort kernels above).
template<bool PACKED, bool SORT>
__global__ __launch_bounds__(256, 2) void ngp_fused(
    const float2* __restrict__ xq,    // [N] (x,y) fp32 (sorted when SORT)
    const float2* __restrict__ tab32, // [16*2^19] (f0,f1) fp32
    const u32*    __restrict__ ctab,  // [16*2^19] packed bf16 pair (d_ws) - PACKED path
    const u32*    __restrict__ perm,  // [N] sorted-pos -> original index (SORT path)
    const float*  __restrict__ w1,    // [34][64]
    const float*  __restrict__ w2,    // [64][64]
    const float*  __restrict__ w3,    // [64][3]
    float* __restrict__ out,          // [N][3]
    int iters)
{
  __shared__ __align__(16) u16   encS[256 * 40];   // 32 bf16 features + 8 pad (80 B stride)
  __shared__ __align__(16) float xyS [256 * 2];    // fp32 x,y per point
  __shared__ __align__(16) u16   hS  [4][2][16*72];// [wave][hi/lo plane][row*72 + col]
  __shared__ __align__(16) s16x8 wS  [10][64];     // shared lo-frags: B2l[c][s]->c*2+s, B3l[s]->8+s

  const int tid  = threadIdx.x;
  const int lane = tid & 63;
  const int wv   = tid >> 6;
  const int m    = lane & 15;   // A row / B,C col
  const int q    = lane >> 4;   // k-quad

  // ---- build B-frags from global fp32 weights (one-time; L2-cached) ----
  float w1x[4], w1y[4];
  s16x8 B1[4], B2h[4][2], B3h[2];
  #pragma unroll
  for (int c = 0; c < 4; ++c) {
    const int n = c*16 + m;
    w1x[c] = w1[n]; w1y[c] = w1[64 + n];
    s16x8 f1;
    #pragma unroll
    for (int j = 0; j < 8; ++j) {               // B1: feature rows 2..33, K=32 exactly
      const int k = q*8 + j;
      f1[j] = (short)f2bf(w1[(2 + k)*64 + n]);
    }
    B1[c] = f1;
    #pragma unroll
    for (int s = 0; s < 2; ++s) {
      s16x8 fh, fl;
      #pragma unroll
      for (int j = 0; j < 8; ++j) {
        const int k = s*32 + q*8 + j;
        const float v = w2[k*64 + n];
        const u16 h = f2bf(v);
        fh[j] = (short)h; fl[j] = (short)f2bf(v - bf2f(h));
      }
      B2h[c][s] = fh;
      if (wv == 0) wS[c*2 + s][lane] = fl;
    }
  }
  #pragma unroll
  for (int s = 0; s < 2; ++s) {
    s16x8 fh, fl;
    #pragma unroll
    for (int j = 0; j < 8; ++j) {
      const int k = s*32 + q*8 + j;
      const float v = (m < 3) ? w3[k*3 + m] : 0.f;
      const u16 h = f2bf(v);
      fh[j] = (short)h; fl[j] = (short)f2bf(v - bf2f(h));
    }
    B3h[s] = fh;
    if (wv == 0) wS[8 + s][lane] = fl;
  }
  __syncthreads();   // once, outside the main loop: publish wS to all waves

  u16* const hpl = &hS[wv][0][0];   // hi plane (this wave)
  u16* const lpl = &hS[wv][1][0];   // lo plane (this wave)

  for (int it = 0; it < iters; ++it) {
    const int base = (blockIdx.x * iters + it) << 8;   // 256 points / iteration

    // ---- phase A: per-thread fp32 encode -> bf16 feature row in LDS ----
    {
      const float2 xy = xq[base + tid];
      ((float2*)xyS)[tid] = xy;
      const float xf = xy.x, yf = xy.y;
      u32 er[16];
      if constexpr (PACKED) {
        // (1) hash levels 12..15: issue all 16 long-latency gathers FIRST
        u32 hv[4][4];
        #pragma unroll
        for (int l = 12; l < 16; ++l) {
          const int res = RESI[l];
          const u32 ix = (u32)floorf(xf * (float)res);
          const u32 iy = (u32)floorf(yf * (float)res);
          const u32 hy = iy * HPRIME, hy1 = hy + HPRIME;
          const u32* t = ctab + (size_t)l * TBL;
          hv[l-12][0] = t[( ix       ^ hy ) & TMASK];
          hv[l-12][1] = t[((ix + 1u) ^ hy ) & TMASK];
          hv[l-12][2] = t[( ix       ^ hy1) & TMASK];
          hv[l-12][3] = t[((ix + 1u) ^ hy1) & TMASK];
        }
        // (2) dense levels 0..11 (L1/L2-hot) while hash gathers fly
        #pragma unroll
        for (int l = 0; l < 12; ++l) {
          const int res = RESI[l];
          const float px = xf * (float)res, py = yf * (float)res;
          const float fx = floorf(px), fy = floorf(py);
          const float wx = px - fx, wy = py - fy;
          const u32 ix = (u32)fx, iy = (u32)fy;
          const float w00 = (1.f-wx)*(1.f-wy), w10 = wx*(1.f-wy);
          const float w01 = (1.f-wx)*wy,       w11 = wx*wy;
          const u32 st  = (u32)res + 1u;
          const u32 i00 = ix + iy*st;
          const u32* t = ctab + (size_t)l * TBL;
          const u32x2a eA = *(const u32x2a*)&t[i00];        // e00 | e10
          const u32x2a eB = *(const u32x2a*)&t[i00 + st];   // e01 | e11
          const float f0 = blo(eA[0])*w00 + blo(eA[1])*w10 + blo(eB[0])*w01 + blo(eB[1])*w11;
          const float f1 = bhi(eA[0])*w00 + bhi(eA[1])*w10 + bhi(eB[0])*w01 + bhi(eB[1])*w11;
          er[l] = cvtpk(f0, f1);
        }
        // (3) consume hash gathers
        #pragma unroll
        for (int hl = 0; hl < 4; ++hl) {
          const int res = RESI[12 + hl];
          const float px = xf * (float)res, py = yf * (float)res;
          const float wx = px - floorf(px), wy = py - floorf(py);
          const float w00 = (1.f-wx)*(1.f-wy), w10 = wx*(1.f-wy);
          const float w01 = (1.f-wx)*wy,       w11 = wx*wy;
          const float f0 = blo(hv[hl][0])*w00 + blo(hv[hl][1])*w10
                         + blo(hv[hl][2])*w01 + blo(hv[hl][3])*w11;
          const float f1 = bhi(hv[hl][0])*w00 + bhi(hv[hl][1])*w10
                         + bhi(hv[hl][2])*w01 + bhi(hv[hl][3])*w11;
          er[12 + hl] = cvtpk(f0, f1);
        }
      } else {
        #pragma unroll
        for (int l = 0; l < 16; ++l) {
          const int res = RESI[l];
          const float px = xf * (float)res, py = yf * (float)res;
          const float fx = floorf(px), fy = floorf(py);
          const float wx = px - fx, wy = py - fy;
          const u32 ix = (u32)fx, iy = (u32)fy;
          const float w00 = (1.f-wx)*(1.f-wy), w10 = wx*(1.f-wy);
          const float w01 = (1.f-wx)*wy,       w11 = wx*wy;
          float f0, f1;
          if (l < 12) {
            const u32 st  = (u32)res + 1u;
            const u32 i00 = ix + iy*st;
            const float2* t = tab32 + (size_t)l * TBL;
            const f32x4a eA = *(const f32x4a*)&t[i00];
            const f32x4a eB = *(const f32x4a*)&t[i00 + st];
            f0 = eA[0]*w00 + eA[2]*w10 + eB[0]*w01 + eB[2]*w11;
            f1 = eA[1]*w00 + eA[3]*w10 + eB[1]*w01 + eB[3]*w11;
          } else {
            const u32 hy = iy * HPRIME, hy1 = hy + HPRIME;
            const u32 i00 = ( ix        ^ hy ) & TMASK;
            const u32 i10 = ((ix + 1u)  ^ hy ) & TMASK;
            const u32 i01 = ( ix        ^ hy1) & TMASK;
            const u32 i11 = ((ix + 1u)  ^ hy1) & TMASK;
            const float2* t = tab32 + (size_t)l * TBL;
            const float2 e00 = t[i00], e10 = t[i10], e01 = t[i01], e11 = t[i11];
            f0 = e00.x*w00 + e10.x*w10 + e01.x*w01 + e11.x*w11;
            f1 = e00.y*w00 + e10.y*w10 + e01.y*w01 + e11.y*w11;
          }
          er[l] = cvtpk(f0, f1);
        }
      }
      uint4* rowp = (uint4*)&encS[tid * 40];
      rowp[0] = make_uint4(er[0],  er[1],  er[2],  er[3]);
      rowp[1] = make_uint4(er[4],  er[5],  er[6],  er[7]);
      rowp[2] = make_uint4(er[8],  er[9],  er[10], er[11]);
      rowp[3] = make_uint4(er[12], er[13], er[14], er[15]);
    }

    // ---- phase B: per-wave MFMA MLP, 4 tiles of 16 points (wave-private, no barriers) ----
    #pragma unroll 1
    for (int t4 = 0; t4 < 4; ++t4) {
      const int rbase = wv*64 + t4*16;
      const s16x8 a1 = *(const s16x8*)&encS[(rbase + m)*40 + q*8];

      float xr[4], yr[4];
      #pragma unroll
      for (int r = 0; r < 4; ++r) {
        const float2 v = ((const float2*)xyS)[rbase + q*4 + r];
        xr[r] = v.x; yr[r] = v.y;
      }

      f32x4 acc[4];
      #pragma unroll
      for (int c = 0; c < 4; ++c) {
        f32x4 z;
        #pragma unroll
        for (int r = 0; r < 4; ++r) z[r] = xr[r]*w1x[c] + yr[r]*w1y[c];  // fp32 x,y path
        acc[c] = MFMA(a1, B1[c], z);
      }

      // relu + hi/lo bf16 split -> u16 planes, stride 72 (write banks 16-spread, ~free)
      #pragma unroll
      for (int c = 0; c < 4; ++c)
        #pragma unroll
        for (int r = 0; r < 4; ++r) {
          const float h = fmaxf(acc[c][r], 0.f);
          const u32 hp_ = cvtpk(h, h);                                  // lo16 = bf16(h)
          const float lf = h - __builtin_bit_cast(float, hp_ << 16);
          const u32 lp_ = cvtpk(lf, lf);
          const int idx = (q*4 + r)*72 + c*16 + m;
          hpl[idx] = (u16)hp_;
          lpl[idx] = (u16)lp_;
        }

      s16x8 hi0 = *(const s16x8*)&hpl[m*72 + q*8];
      s16x8 hi1 = *(const s16x8*)&hpl[m*72 + 32 + q*8];
      s16x8 lo0 = *(const s16x8*)&lpl[m*72 + q*8];
      s16x8 lo1 = *(const s16x8*)&lpl[m*72 + 32 + q*8];

      #pragma unroll
      for (int c = 0; c < 4; ++c) {
        const s16x8 b2l0 = wS[c*2 + 0][lane];   // cold lo-frags from shared LDS
        const s16x8 b2l1 = wS[c*2 + 1][lane];
        f32x4 z = {0.f,0.f,0.f,0.f};
        z = MFMA(hi0, B2h[c][0], z); z = MFMA(hi1, B2h[c][1], z);
        z = MFMA(lo0, B2h[c][0], z); z = MFMA(lo1, B2h[c][1], z);
        z = MFMA(hi0, b2l0,      z); z = MFMA(hi1, b2l1,      z);
        acc[c] = z;
      }

      #pragma unroll
      for (int c = 0; c < 4; ++c)
        #pragma unroll
        for (int r = 0; r < 4; ++r) {
          const float h = fmaxf(acc[c][r], 0.f);
          const u32 hp_ = cvtpk(h, h);
          const float lf = h - __builtin_bit_cast(float, hp_ << 16);
          const u32 lp_ = cvtpk(lf, lf);
          const int idx = (q*4 + r)*72 + c*16 + m;
          hpl[idx] = (u16)hp_;
          lpl[idx] = (u16)lp_;
        }

      hi0 = *(const s16x8*)&hpl[m*72 + q*8];
      hi1 = *(const s16x8*)&hpl[m*72 + 32 + q*8];
      lo0 = *(const s16x8*)&lpl[m*72 + q*8];
      lo1 = *(const s16x8*)&lpl[m*72 + 32 + q*8];

      const s16x8 b3l0 = wS[8][lane];
      const s16x8 b3l1 = wS[9][lane];
      f32x4 z = {0.f,0.f,0.f,0.f};
      z = MFMA(hi0, B3h[0], z); z = MFMA(hi1, B3h[1], z);
      z = MFMA(lo0, B3h[0], z); z = MFMA(lo1, B3h[1], z);
      z = MFMA(hi0, b3l0,   z); z = MFMA(hi1, b3l1,   z);

      if (m < 3) {   // C: row = q*4+r, col = m
        #pragma unroll
        for (int r = 0; r < 4; ++r) {
          const int pi = base + rbase + q*4 + r;
          const size_t oi = SORT ? (size_t)perm[pi] : (size_t)pi;
          out[oi*3 + m] = z[r];
        }
      }
    }
  }
}

extern "C" void kernel_launch(void* const* d_in, const int* in_sizes, int n_in,
                              void* d_out, int out_size, void* d_ws, size_t ws_size,
                              hipStream_t stream) {
  const int N = in_sizes[0] / 2;            // 2^21 points
  const int ITERS = 4;
  const int blocks = N / (256 * ITERS);     // 2048 blocks
  // workspace layout
  const size_t ctab_b = (size_t)16 * TBL * 4;          // 32 MB packed tables
  const size_t xs_off  = ctab_b;                       // sorted points, 16 MB
  const size_t perm_off = xs_off + (size_t)N * 8;      // perm, 8 MB
  const size_t hist_off = perm_off + (size_t)N * 4;    // 64K bins, 256 KB
  const size_t sort_need = hist_off + (size_t)NBINS * 4;

  char* ws = (char*)d_ws;
  if (ws_size >= sort_need) {
    cvt_tab<<<2048, 256, 0, stream>>>((const float4*)d_in[1], (uint2*)d_ws, (int)(16*TBL/2));
    u32* hist = (u32*)(ws + hist_off);
    float2* xs = (float2*)(ws + xs_off);
    u32* perm  = (u32*)(ws + perm_off);
    hipMemsetAsync(hist, 0, (size_t)NBINS * 4, stream);
    hist_k<<<2048, 256, 0, stream>>>((const float2*)d_in[0], hist, N);
    scan_k<<<1, 1024, 0, stream>>>(hist);
    scat_k<<<2048, 256, 0, stream>>>((const float2*)d_in[0], hist, xs, perm, N);
    ngp_fused<true, true><<<blocks, 256, 0, stream>>>(
        xs, (const float2*)d_in[1], (const u32*)d_ws, perm,
        (const float*)d_in[2], (const float*)d_in[3], (const float*)d_in[4],
        (float*)d_out, ITERS);
  } else if (ws_size >= ctab_b) {
    cvt_tab<<<2048, 256, 0, stream>>>((const float4*)d_in[1], (uint2*)d_ws, (int)(16*TBL/2));
    ngp_fused<true, false><<<blocks, 256, 0, stream>>>(
        (const float2*)d_in[0], (const float2*)d_in[1], (const u32*)d_ws, nullptr,
        (const float*)d_in[2], (const float*)d_in[3], (const float*)d_in[4],
        (float*)d_out, ITERS);
  } else {
    ngp_fused<false, false><<<blocks, 256, 0, stream>>>(
        (const float2*)d_in[0], (const float2*)d_in[1], (const u32*)d_ws, nullptr,
        (const float*)d_in[2], (const float*)d_in[3], (const float*)d_in[4],
        (float*)d_out, ITERS);
  }
}

// Round 7
// 402.004 us; speedup vs baseline: 1.3308x; 1.3308x over previous
//
#include <hip/hip_runtime.h>

typedef unsigned int u32;
typedef unsigned short u16;
typedef __attribute__((ext_vector_type(8))) short s16x8;
typedef __attribute__((ext_vector_type(4))) float f32x4;
typedef float f32x4a __attribute__((ext_vector_type(4), aligned(8)));  // 8B-aligned 16B load

#define TBL    524288u
#define TMASK  (TBL - 1u)
#define HPRIME 2654435761u
#define NBINS  32768            // 256 x 128 Morton bins (~64 pts/bin)
#define NBLK   128              // sort blocks; bh table = NBLK*NBINS*4 = 16 MB

// res[l] = floor(16 * 1.3819^l); dense (linear) while (res+1)^2 <= 2^19 -> levels 0..11
__device__ constexpr int RESI[16] = {16,22,30,42,58,80,111,153,212,294,406,561,775,1072,1481,2047};

static __device__ __forceinline__ u16 f2bf(float f){            // RNE f32->bf16 (manual)
  u32 u = __builtin_bit_cast(u32, f);
  return (u16)((u + 0x7fffu + ((u >> 16) & 1u)) >> 16);
}
static __device__ __forceinline__ float bf2f(u16 h){ return __builtin_bit_cast(float, (u32)h << 16); }
static __device__ __forceinline__ float blo(u32 e){ return __builtin_bit_cast(float, (u32)(e << 16)); }
static __device__ __forceinline__ float bhi(u32 e){ return __builtin_bit_cast(float, (u32)(e & 0xffff0000u)); }
static __device__ __forceinline__ u32 packbf2(float a, float b){ return (u32)f2bf(a) | ((u32)f2bf(b) << 16); }
// HW packed RNE f32->bf16 (gfx950): D.lo = bf16(a), D.hi = bf16(b). Same rounding as f2bf.
static __device__ __forceinline__ u32 cvtpk(float a, float b){
  u32 r; asm("v_cvt_pk_bf16_f32 %0, %1, %2" : "=v"(r) : "v"(a), "v"(b)); return r;
}
static __device__ __forceinline__ u32 spread8(u32 v){
  v &= 0xFFu;
  v = (v | (v << 4)) & 0x0F0Fu;
  v = (v | (v << 2)) & 0x3333u;
  v = (v | (v << 1)) & 0x5555u;
  return v;
}
// 15-bit Morton key: 8 bits x (256 cols), 7 bits y (128 rows) -> key < 32768
static __device__ __forceinline__ u32 mkey(float x, float y){
  u32 kx = (u32)(x * 256.f); kx = kx > 255u ? 255u : kx;
  u32 ky = (u32)(y * 128.f); ky = ky > 127u ? 127u : ky;
  return spread8(kx) | (spread8(ky) << 1);
}

#define MFMA(A,B,C) __builtin_amdgcn_mfma_f32_16x16x32_bf16((A),(B),(C),0,0,0)

// R13 pre-pass: pack ONLY hash levels 12..15 to bf16 (8 MB). Dense levels read fp32
// directly: with Morton-sorted points their working set per block is a handful of lines
// (L1-hot), so packing them bought nothing but 48 MB of cvt traffic.
__global__ __launch_bounds__(256) void cvt_tab(const float4* __restrict__ src,
                                               uint2* __restrict__ dst, int n4) {
  for (int i = blockIdx.x*256 + threadIdx.x; i < n4; i += gridDim.x*256) {
    const float4 v = src[i];
    dst[i] = make_uint2(packbf2(v.x, v.y), packbf2(v.z, v.w));
  }
}

// ---------------- R13 atomic-free Morton counting sort ----------------
// R12's sort won the main kernel 336->176 us but its pre-passes cost ~260 us: 4M
// device-scope atomics (hist + scatter-with-return) bypass L2 on CDNA -> HBM-latency RMWs.
// R13: block-aggregated sort. All atomics are LDS-local; zero global atomics; no memset.
__global__ __launch_bounds__(256) void histb_k(const float2* __restrict__ xq,
                                               u32* __restrict__ bh, int ppb) {
  __shared__ u32 cnt[NBINS];                       // 128 KB -> 1 block/CU (fine, 128 blocks)
  const int j = blockIdx.x;
  for (int i = threadIdx.x; i < NBINS; i += 256) cnt[i] = 0;
  __syncthreads();
  const float2* p = xq + (size_t)j * ppb;
  for (int i = threadIdx.x; i < ppb; i += 256) {
    const float2 v = p[i];
    atomicAdd(&cnt[mkey(v.x, v.y)], 1u);           // LDS atomic (CU-local, cheap)
  }
  __syncthreads();
  u32* o = bh + (size_t)j * NBINS;
  for (int i = threadIdx.x; i < NBINS; i += 256) o[i] = cnt[i];
}
// in-place per-bin exclusive scan over blocks: bh[j][b] <- sum_{j'<j} cnt; tot[b] = total
__global__ __launch_bounds__(256) void scanb_k(u32* __restrict__ bh, u32* __restrict__ tot) {
  const int b = blockIdx.x*256 + threadIdx.x;      // NBINS threads, coalesced per j
  u32 run = 0;
  for (int j = 0; j < NBLK; ++j) {
    const size_t k = (size_t)j * NBINS + b;
    const u32 v = bh[k]; bh[k] = run; run += v;
  }
  tot[b] = run;
}
// single-block exclusive scan of the 32768 bin totals -> bin start offsets (in place)
__global__ __launch_bounds__(1024) void scant_k(u32* __restrict__ tot) {
  __shared__ u32 part[1024];
  const int t = threadIdx.x;
  u32 loc[32]; u32 s = 0;
  #pragma unroll
  for (int i = 0; i < 32; ++i) { loc[i] = tot[t*32 + i]; s += loc[i]; }
  part[t] = s;
  __syncthreads();
  for (int d = 1; d < 1024; d <<= 1) {
    const u32 v = (t >= d) ? part[t - d] : 0u;
    __syncthreads();
    part[t] += v;
    __syncthreads();
  }
  u32 run = part[t] - s;                           // exclusive prefix of this thread's chunk
  #pragma unroll
  for (int i = 0; i < 32; ++i) { tot[t*32 + i] = run; run += loc[i]; }
}
__global__ __launch_bounds__(256) void scatb_k(const float2* __restrict__ xq,
                                               const u32* __restrict__ bh,
                                               const u32* __restrict__ binst,
                                               float2* __restrict__ xs,
                                               u32* __restrict__ perm, int ppb) {
  __shared__ u32 offs[NBINS];                      // this block's global write cursors
  const int j = blockIdx.x;
  for (int i = threadIdx.x; i < NBINS; i += 256)
    offs[i] = bh[(size_t)j * NBINS + i] + binst[i];
  __syncthreads();
  const size_t base = (size_t)j * ppb;
  for (int i = threadIdx.x; i < ppb; i += 256) {
    const float2 pt = xq[base + i];
    const u32 pos = atomicAdd(&offs[mkey(pt.x, pt.y)], 1u);   // LDS atomic-return
    xs[pos] = pt;
    perm[pos] = (u32)(base + i);
  }
}

// Fused instant-NGP: fp32 hash-grid encode (per-thread) + 34->64->64->3 MLP via bf16-split MFMA.
// OCCUPANCY MODEL (verified R8/R9/R10): 3 blocks/CU iff arch VGPR <= ~104 AND LDS <= 53248 B.
// History: 515(R2)->443(R5)->392(R6)->375(R8)->363(R10)->336(R11)->176 main/535 total (R12
// Morton sort: FETCH 743->59MB, conflicts 4.7M via stride-72 - but naive sort cost 260us).
// R13: atomic-free sort pre-passes + hash-only ctab.
template<bool PACKED, bool SORT>
__global__ __launch_bounds__(256, 2) void ngp_fused(
    const float2* __restrict__ xq,    // [N] (x,y) fp32 (sorted when SORT)
    const float2* __restrict__ tab32, // [16*2^19] (f0,f1) fp32
    const u32*    __restrict__ ctab,  // [4*2^19] packed bf16 pair, levels 12..15 (d_ws)
    const u32*    __restrict__ perm,  // [N] sorted-pos -> original index (SORT path)
    const float*  __restrict__ w1,    // [34][64]
    const float*  __restrict__ w2,    // [64][64]
    const float*  __restrict__ w3,    // [64][3]
    float* __restrict__ out,          // [N][3]
    int iters)
{
  __shared__ __align__(16) u16   encS[256 * 40];   // 32 bf16 features + 8 pad (80 B stride)
  __shared__ __align__(16) float xyS [256 * 2];    // fp32 x,y per point
  __shared__ __align__(16) u16   hS  [4][2][16*72];// [wave][hi/lo plane][row*72 + col]
  __shared__ __align__(16) s16x8 wS  [10][64];     // shared lo-frags: B2l[c][s]->c*2+s, B3l[s]->8+s

  const int tid  = threadIdx.x;
  const int lane = tid & 63;
  const int wv   = tid >> 6;
  const int m    = lane & 15;   // A row / B,C col
  const int q    = lane >> 4;   // k-quad

  // ---- build B-frags from global fp32 weights (one-time; L2-cached) ----
  float w1x[4], w1y[4];
  s16x8 B1[4], B2h[4][2], B3h[2];
  #pragma unroll
  for (int c = 0; c < 4; ++c) {
    const int n = c*16 + m;
    w1x[c] = w1[n]; w1y[c] = w1[64 + n];
    s16x8 f1;
    #pragma unroll
    for (int j = 0; j < 8; ++j) {               // B1: feature rows 2..33, K=32 exactly
      const int k = q*8 + j;
      f1[j] = (short)f2bf(w1[(2 + k)*64 + n]);
    }
    B1[c] = f1;
    #pragma unroll
    for (int s = 0; s < 2; ++s) {
      s16x8 fh, fl;
      #pragma unroll
      for (int j = 0; j < 8; ++j) {
        const int k = s*32 + q*8 + j;
        const float v = w2[k*64 + n];
        const u16 h = f2bf(v);
        fh[j] = (short)h; fl[j] = (short)f2bf(v - bf2f(h));
      }
      B2h[c][s] = fh;
      if (wv == 0) wS[c*2 + s][lane] = fl;
    }
  }
  #pragma unroll
  for (int s = 0; s < 2; ++s) {
    s16x8 fh, fl;
    #pragma unroll
    for (int j = 0; j < 8; ++j) {
      const int k = s*32 + q*8 + j;
      const float v = (m < 3) ? w3[k*3 + m] : 0.f;
      const u16 h = f2bf(v);
      fh[j] = (short)h; fl[j] = (short)f2bf(v - bf2f(h));
    }
    B3h[s] = fh;
    if (wv == 0) wS[8 + s][lane] = fl;
  }
  __syncthreads();   // once, outside the main loop: publish wS to all waves

  u16* const hpl = &hS[wv][0][0];   // hi plane (this wave)
  u16* const lpl = &hS[wv][1][0];   // lo plane (this wave)

  for (int it = 0; it < iters; ++it) {
    const int base = (blockIdx.x * iters + it) << 8;   // 256 points / iteration

    // ---- phase A: per-thread fp32 encode -> bf16 feature row in LDS ----
    {
      const float2 xy = xq[base + tid];
      ((float2*)xyS)[tid] = xy;
      const float xf = xy.x, yf = xy.y;
      u32 er[16];
      // (1) hash levels 12..15: issue all 16 long-latency gathers FIRST
      u32 hv[4][4];
      float2 hv32[4][4];
      #pragma unroll
      for (int l = 12; l < 16; ++l) {
        const int res = RESI[l];
        const u32 ix = (u32)floorf(xf * (float)res);
        const u32 iy = (u32)floorf(yf * (float)res);
        const u32 hy = iy * HPRIME, hy1 = hy + HPRIME;
        const u32 i0 = ( ix       ^ hy ) & TMASK;
        const u32 i1 = ((ix + 1u) ^ hy ) & TMASK;
        const u32 i2 = ( ix       ^ hy1) & TMASK;
        const u32 i3 = ((ix + 1u) ^ hy1) & TMASK;
        if constexpr (PACKED) {
          const u32* t = ctab + (size_t)(l - 12) * TBL;
          hv[l-12][0] = t[i0]; hv[l-12][1] = t[i1];
          hv[l-12][2] = t[i2]; hv[l-12][3] = t[i3];
        } else {
          const float2* t = tab32 + (size_t)l * TBL;
          hv32[l-12][0] = t[i0]; hv32[l-12][1] = t[i1];
          hv32[l-12][2] = t[i2]; hv32[l-12][3] = t[i3];
        }
      }
      // (2) dense levels 0..11: fp32 paired corner loads (L1-hot under sort) while hash flies
      #pragma unroll
      for (int l = 0; l < 12; ++l) {
        const int res = RESI[l];
        const float px = xf * (float)res, py = yf * (float)res;
        const float fx = floorf(px), fy = floorf(py);
        const float wx = px - fx, wy = py - fy;
        const u32 ix = (u32)fx, iy = (u32)fy;
        const float w00 = (1.f-wx)*(1.f-wy), w10 = wx*(1.f-wy);
        const float w01 = (1.f-wx)*wy,       w11 = wx*wy;
        const u32 st  = (u32)res + 1u;
        const u32 i00 = ix + iy*st;
        const float2* t = tab32 + (size_t)l * TBL;
        const f32x4a eA = *(const f32x4a*)&t[i00];        // e00 | e10
        const f32x4a eB = *(const f32x4a*)&t[i00 + st];   // e01 | e11
        const float f0 = eA[0]*w00 + eA[2]*w10 + eB[0]*w01 + eB[2]*w11;
        const float f1 = eA[1]*w00 + eA[3]*w10 + eB[1]*w01 + eB[3]*w11;
        er[l] = cvtpk(f0, f1);
      }
      // (3) consume hash gathers
      #pragma unroll
      for (int hl = 0; hl < 4; ++hl) {
        const int res = RESI[12 + hl];
        const float px = xf * (float)res, py = yf * (float)res;
        const float wx = px - floorf(px), wy = py - floorf(py);
        const float w00 = (1.f-wx)*(1.f-wy), w10 = wx*(1.f-wy);
        const float w01 = (1.f-wx)*wy,       w11 = wx*wy;
        float f0, f1;
        if constexpr (PACKED) {
          f0 = blo(hv[hl][0])*w00 + blo(hv[hl][1])*w10
             + blo(hv[hl][2])*w01 + blo(hv[hl][3])*w11;
          f1 = bhi(hv[hl][0])*w00 + bhi(hv[hl][1])*w10
             + bhi(hv[hl][2])*w01 + bhi(hv[hl][3])*w11;
        } else {
          f0 = hv32[hl][0].x*w00 + hv32[hl][1].x*w10 + hv32[hl][2].x*w01 + hv32[hl][3].x*w11;
          f1 = hv32[hl][0].y*w00 + hv32[hl][1].y*w10 + hv32[hl][2].y*w01 + hv32[hl][3].y*w11;
        }
        er[12 + hl] = cvtpk(f0, f1);
      }
      uint4* rowp = (uint4*)&encS[tid * 40];
      rowp[0] = make_uint4(er[0],  er[1],  er[2],  er[3]);
      rowp[1] = make_uint4(er[4],  er[5],  er[6],  er[7]);
      rowp[2] = make_uint4(er[8],  er[9],  er[10], er[11]);
      rowp[3] = make_uint4(er[12], er[13], er[14], er[15]);
    }

    // ---- phase B: per-wave MFMA MLP, 4 tiles of 16 points (wave-private, no barriers) ----
    #pragma unroll 1
    for (int t4 = 0; t4 < 4; ++t4) {
      const int rbase = wv*64 + t4*16;
      const s16x8 a1 = *(const s16x8*)&encS[(rbase + m)*40 + q*8];

      float xr[4], yr[4];
      #pragma unroll
      for (int r = 0; r < 4; ++r) {
        const float2 v = ((const float2*)xyS)[rbase + q*4 + r];
        xr[r] = v.x; yr[r] = v.y;
      }

      f32x4 acc[4];
      #pragma unroll
      for (int c = 0; c < 4; ++c) {
        f32x4 z;
        #pragma unroll
        for (int r = 0; r < 4; ++r) z[r] = xr[r]*w1x[c] + yr[r]*w1y[c];  // fp32 x,y path
        acc[c] = MFMA(a1, B1[c], z);
      }

      // relu + hi/lo bf16 split -> u16 planes, stride 72 (write banks 16-spread, ~free)
      #pragma unroll
      for (int c = 0; c < 4; ++c)
        #pragma unroll
        for (int r = 0; r < 4; ++r) {
          const float h = fmaxf(acc[c][r], 0.f);
          const u32 hp_ = cvtpk(h, h);                                  // lo16 = bf16(h)
          const float lf = h - __builtin_bit_cast(float, hp_ << 16);
          const u32 lp_ = cvtpk(lf, lf);
          const int idx = (q*4 + r)*72 + c*16 + m;
          hpl[idx] = (u16)hp_;
          lpl[idx] = (u16)lp_;
        }

      s16x8 hi0 = *(const s16x8*)&hpl[m*72 + q*8];
      s16x8 hi1 = *(const s16x8*)&hpl[m*72 + 32 + q*8];
      s16x8 lo0 = *(const s16x8*)&lpl[m*72 + q*8];
      s16x8 lo1 = *(const s16x8*)&lpl[m*72 + 32 + q*8];

      #pragma unroll
      for (int c = 0; c < 4; ++c) {
        const s16x8 b2l0 = wS[c*2 + 0][lane];   // cold lo-frags from shared LDS
        const s16x8 b2l1 = wS[c*2 + 1][lane];
        f32x4 z = {0.f,0.f,0.f,0.f};
        z = MFMA(hi0, B2h[c][0], z); z = MFMA(hi1, B2h[c][1], z);
        z = MFMA(lo0, B2h[c][0], z); z = MFMA(lo1, B2h[c][1], z);
        z = MFMA(hi0, b2l0,      z); z = MFMA(hi1, b2l1,      z);
        acc[c] = z;
      }

      #pragma unroll
      for (int c = 0; c < 4; ++c)
        #pragma unroll
        for (int r = 0; r < 4; ++r) {
          const float h = fmaxf(acc[c][r], 0.f);
          const u32 hp_ = cvtpk(h, h);
          const float lf = h - __builtin_bit_cast(float, hp_ << 16);
          const u32 lp_ = cvtpk(lf, lf);
          const int idx = (q*4 + r)*72 + c*16 + m;
          hpl[idx] = (u16)hp_;
          lpl[idx] = (u16)lp_;
        }

      hi0 = *(const s16x8*)&hpl[m*72 + q*8];
      hi1 = *(const s16x8*)&hpl[m*72 + 32 + q*8];
      lo0 = *(const s16x8*)&lpl[m*72 + q*8];
      lo1 = *(const s16x8*)&lpl[m*72 + 32 + q*8];

      const s16x8 b3l0 = wS[8][lane];
      const s16x8 b3l1 = wS[9][lane];
      f32x4 z = {0.f,0.f,0.f,0.f};
      z = MFMA(hi0, B3h[0], z); z = MFMA(hi1, B3h[1], z);
      z = MFMA(lo0, B3h[0], z); z = MFMA(lo1, B3h[1], z);
      z = MFMA(hi0, b3l0,   z); z = MFMA(hi1, b3l1,   z);

      if (m < 3) {   // C: row = q*4+r, col = m
        #pragma unroll
        for (int r = 0; r < 4; ++r) {
          const int pi = base + rbase + q*4 + r;
          const size_t oi = SORT ? (size_t)perm[pi] : (size_t)pi;
          out[oi*3 + m] = z[r];
        }
      }
    }
  }
}

extern "C" void kernel_launch(void* const* d_in, const int* in_sizes, int n_in,
                              void* d_out, int out_size, void* d_ws, size_t ws_size,
                              hipStream_t stream) {
  const int N = in_sizes[0] / 2;            // 2^21 points
  const int ITERS = 4;
  const int blocks = N / (256 * ITERS);     // 2048 blocks
  // workspace layout (48.3 MB total; R12 proved >= 56.25 MB exists)
  const size_t ctab_b   = (size_t)4 * TBL * 4;             // 8 MB packed hash tables (12..15)
  const size_t xs_off   = ctab_b;                          // sorted points, 16 MB
  const size_t perm_off = xs_off + (size_t)N * 8;          // perm, 8 MB
  const size_t bh_off   = perm_off + (size_t)N * 4;        // per-block histograms, 16 MB
  const size_t tot_off  = bh_off + (size_t)NBLK * NBINS * 4;
  const size_t need     = tot_off + (size_t)NBINS * 4;     // + 128 KB

  char* ws = (char*)d_ws;
  if (ws_size >= need && (N % NBLK) == 0) {
    const int ppb = N / NBLK;
    // level-12 entries start at float4 index 12*TBL/2; 4 levels = 2*TBL float4s
    cvt_tab<<<1024, 256, 0, stream>>>(((const float4*)d_in[1]) + (size_t)6*TBL,
                                      (uint2*)d_ws, (int)(2*TBL));
    u32* bh    = (u32*)(ws + bh_off);
    u32* tot   = (u32*)(ws + tot_off);
    float2* xs = (float2*)(ws + xs_off);
    u32* perm  = (u32*)(ws + perm_off);
    histb_k<<<NBLK, 256, 0, stream>>>((const float2*)d_in[0], bh, ppb);
    scanb_k<<<NBINS/256, 256, 0, stream>>>(bh, tot);
    scant_k<<<1, 1024, 0, stream>>>(tot);
    scatb_k<<<NBLK, 256, 0, stream>>>((const float2*)d_in[0], bh, tot, xs, perm, ppb);
    ngp_fused<true, true><<<blocks, 256, 0, stream>>>(
        xs, (const float2*)d_in[1], (const u32*)d_ws, perm,
        (const float*)d_in[2], (const float*)d_in[3], (const float*)d_in[4],
        (float*)d_out, ITERS);
  } else if (ws_size >= ctab_b) {
    cvt_tab<<<1024, 256, 0, stream>>>(((const float4*)d_in[1]) + (size_t)6*TBL,
                                      (uint2*)d_ws, (int)(2*TBL));
    ngp_fused<true, false><<<blocks, 256, 0, stream>>>(
        (const float2*)d_in[0], (const float2*)d_in[1], (const u32*)d_ws, nullptr,
        (const float*)d_in[2], (const float*)d_in[3], (const float*)d_in[4],
        (float*)d_out, ITERS);
  } else {
    ngp_fused<false, false><<<blocks, 256, 0, stream>>>(
        (const float2*)d_in[0], (const float2*)d_in[1], (const u32*)d_ws, nullptr,
        (const float*)d_in[2], (const float*)d_in[3], (const float*)d_in[4],
        (float*)d_out, ITERS);
  }
}

// Round 8
// 377.068 us; speedup vs baseline: 1.4188x; 1.0661x over previous
//
#include <hip/hip_runtime.h>

typedef unsigned int u32;
typedef unsigned short u16;
typedef __attribute__((ext_vector_type(8))) short s16x8;
typedef __attribute__((ext_vector_type(4))) float f32x4;
typedef float f32x4a __attribute__((ext_vector_type(4), aligned(8)));  // 8B-aligned 16B load
typedef u32  u32x2a  __attribute__((ext_vector_type(2), aligned(4)));  // 4B-aligned 8B load

#define TBL    524288u
#define TMASK  (TBL - 1u)
#define HPRIME 2654435761u
#define NBINS  16384            // 128 x 128 Morton bins (~128 pts/bin)
#define NBLK   256              // sort blocks; ppb = 8192; bh = NBLK*NBINS*4 = 16 MB

// res[l] = floor(16 * 1.3819^l); dense (linear) while (res+1)^2 <= 2^19 -> levels 0..11
__device__ constexpr int RESI[16] = {16,22,30,42,58,80,111,153,212,294,406,561,775,1072,1481,2047};

static __device__ __forceinline__ u16 f2bf(float f){            // RNE f32->bf16 (manual)
  u32 u = __builtin_bit_cast(u32, f);
  return (u16)((u + 0x7fffu + ((u >> 16) & 1u)) >> 16);
}
static __device__ __forceinline__ float bf2f(u16 h){ return __builtin_bit_cast(float, (u32)h << 16); }
static __device__ __forceinline__ float blo(u32 e){ return __builtin_bit_cast(float, (u32)(e << 16)); }
static __device__ __forceinline__ float bhi(u32 e){ return __builtin_bit_cast(float, (u32)(e & 0xffff0000u)); }
static __device__ __forceinline__ u32 packbf2(float a, float b){ return (u32)f2bf(a) | ((u32)f2bf(b) << 16); }
// HW packed RNE f32->bf16 (gfx950): D.lo = bf16(a), D.hi = bf16(b). Same rounding as f2bf.
static __device__ __forceinline__ u32 cvtpk(float a, float b){
  u32 r; asm("v_cvt_pk_bf16_f32 %0, %1, %2" : "=v"(r) : "v"(a), "v"(b)); return r;
}
static __device__ __forceinline__ u32 spread8(u32 v){
  v &= 0xFFu;
  v = (v | (v << 4)) & 0x0F0Fu;
  v = (v | (v << 2)) & 0x3333u;
  v = (v | (v << 1)) & 0x5555u;
  return v;
}
// 14-bit Morton key: 7 bits x, 7 bits y (128x128) -> key < 16384
static __device__ __forceinline__ u32 mkey(float x, float y){
  u32 kx = (u32)(x * 128.f); kx = kx > 127u ? 127u : kx;
  u32 ky = (u32)(y * 128.f); ky = ky > 127u ? 127u : ky;
  return spread8(kx) | (spread8(ky) << 1);
}

#define MFMA(A,B,C) __builtin_amdgcn_mfma_f32_16x16x32_bf16((A),(B),(C),0,0,0)

// R14 pre-pass: pack levels 8..15 to bf16 (16 MB). Levels 0..7 (~330 KB fp32) are L1-hot
// as fp32. R13 proved 8..11 DO need packing (dense-fp32 cost main 176->197, FETCH 59->92).
__global__ __launch_bounds__(256) void cvt_tab(const float4* __restrict__ src,
                                               uint2* __restrict__ dst, int n4) {
  for (int i = blockIdx.x*256 + threadIdx.x; i < n4; i += gridDim.x*256) {
    const float4 v = src[i];
    dst[i] = make_uint2(packbf2(v.x, v.y), packbf2(v.z, v.w));
  }
}

// ---------------- R14 atomic-free Morton counting sort ----------------
// R13's sort (128 blocks x 128KB LDS) was occupancy-starved: 1 blk/CU on HALF the CUs.
// R14: NBINS 16384 -> 64KB LDS, NBLK 256 -> every CU busy. All atomics LDS-local.
__global__ __launch_bounds__(256) void histb_k(const float2* __restrict__ xq,
                                               u32* __restrict__ bh, int ppb) {
  __shared__ u32 cnt[NBINS];                       // 64 KB
  const int j = blockIdx.x;
  for (int i = threadIdx.x; i < NBINS; i += 256) cnt[i] = 0;
  __syncthreads();
  const float2* p = xq + (size_t)j * ppb;
  for (int i = threadIdx.x; i < ppb; i += 256) {
    const float2 v = p[i];
    atomicAdd(&cnt[mkey(v.x, v.y)], 1u);           // LDS atomic (CU-local)
  }
  __syncthreads();
  u32* o = bh + (size_t)j * NBINS;
  for (int i = threadIdx.x; i < NBINS; i += 256) o[i] = cnt[i];
}
// in-place per-bin exclusive scan over blocks: bh[j][b] <- sum_{j'<j} cnt; tot[b] = total
__global__ __launch_bounds__(256) void scanb_k(u32* __restrict__ bh, u32* __restrict__ tot) {
  const int b = blockIdx.x*256 + threadIdx.x;      // NBINS threads, coalesced per j
  u32 run = 0;
  for (int j = 0; j < NBLK; ++j) {
    const size_t k = (size_t)j * NBINS + b;
    const u32 v = bh[k]; bh[k] = run; run += v;
  }
  tot[b] = run;
}
// single-block exclusive scan of the 16384 bin totals -> bin start offsets (in place)
__global__ __launch_bounds__(1024) void scant_k(u32* __restrict__ tot) {
  __shared__ u32 part[1024];
  const int t = threadIdx.x;
  u32 loc[16]; u32 s = 0;
  #pragma unroll
  for (int i = 0; i < 16; ++i) { loc[i] = tot[t*16 + i]; s += loc[i]; }
  part[t] = s;
  __syncthreads();
  for (int d = 1; d < 1024; d <<= 1) {
    const u32 v = (t >= d) ? part[t - d] : 0u;
    __syncthreads();
    part[t] += v;
    __syncthreads();
  }
  u32 run = part[t] - s;                           // exclusive prefix of this thread's chunk
  #pragma unroll
  for (int i = 0; i < 16; ++i) { tot[t*16 + i] = run; run += loc[i]; }
}
__global__ __launch_bounds__(256) void scatb_k(const float2* __restrict__ xq,
                                               const u32* __restrict__ bh,
                                               const u32* __restrict__ binst,
                                               float2* __restrict__ xs,
                                               u32* __restrict__ perm, int ppb) {
  __shared__ u32 offs[NBINS];                      // this block's global write cursors, 64 KB
  const int j = blockIdx.x;
  for (int i = threadIdx.x; i < NBINS; i += 256)
    offs[i] = bh[(size_t)j * NBINS + i] + binst[i];
  __syncthreads();
  const size_t base = (size_t)j * ppb;
  for (int i = threadIdx.x; i < ppb; i += 256) {
    const float2 pt = xq[base + i];
    const u32 pos = atomicAdd(&offs[mkey(pt.x, pt.y)], 1u);   // LDS atomic-return
    xs[pos] = pt;                                  // scattered 8B; L2 (32MB > out) absorbs
    perm[pos] = (u32)(base + i);
  }
}

// Fused instant-NGP: fp32 hash-grid encode (per-thread) + 34->64->64->3 MLP via bf16-split MFMA.
// OCCUPANCY MODEL (verified R8/R9/R10): 3 blocks/CU iff arch VGPR <= ~104 AND LDS <= 53248 B.
// History: 515(R2)->443(R5)->392(R6)->375(R8)->363(R10)->336(R11)->176 main/535 total (R12
// Morton sort, FETCH 743->59MB)->197 main/402 total (R13 cheap sort but dense-fp32 regression).
// R14: ctab covers levels 8..15 (uniform index (l-8)*TBL); 0..7 fp32.
template<bool PACKED, bool SORT>
__global__ __launch_bounds__(256, 2) void ngp_fused(
    const float2* __restrict__ xq,    // [N] (x,y) fp32 (sorted when SORT)
    const float2* __restrict__ tab32, // [16*2^19] (f0,f1) fp32
    const u32*    __restrict__ ctab,  // [8*2^19] packed bf16 pair, levels 8..15 (d_ws)
    const u32*    __restrict__ perm,  // [N] sorted-pos -> original index (SORT path)
    const float*  __restrict__ w1,    // [34][64]
    const float*  __restrict__ w2,    // [64][64]
    const float*  __restrict__ w3,    // [64][3]
    float* __restrict__ out,          // [N][3]
    int iters)
{
  __shared__ __align__(16) u16   encS[256 * 40];   // 32 bf16 features + 8 pad (80 B stride)
  __shared__ __align__(16) float xyS [256 * 2];    // fp32 x,y per point
  __shared__ __align__(16) u16   hS  [4][2][16*72];// [wave][hi/lo plane][row*72 + col]
  __shared__ __align__(16) s16x8 wS  [10][64];     // shared lo-frags: B2l[c][s]->c*2+s, B3l[s]->8+s

  const int tid  = threadIdx.x;
  const int lane = tid & 63;
  const int wv   = tid >> 6;
  const int m    = lane & 15;   // A row / B,C col
  const int q    = lane >> 4;   // k-quad

  // ---- build B-frags from global fp32 weights (one-time; L2-cached) ----
  float w1x[4], w1y[4];
  s16x8 B1[4], B2h[4][2], B3h[2];
  #pragma unroll
  for (int c = 0; c < 4; ++c) {
    const int n = c*16 + m;
    w1x[c] = w1[n]; w1y[c] = w1[64 + n];
    s16x8 f1;
    #pragma unroll
    for (int j = 0; j < 8; ++j) {               // B1: feature rows 2..33, K=32 exactly
      const int k = q*8 + j;
      f1[j] = (short)f2bf(w1[(2 + k)*64 + n]);
    }
    B1[c] = f1;
    #pragma unroll
    for (int s = 0; s < 2; ++s) {
      s16x8 fh, fl;
      #pragma unroll
      for (int j = 0; j < 8; ++j) {
        const int k = s*32 + q*8 + j;
        const float v = w2[k*64 + n];
        const u16 h = f2bf(v);
        fh[j] = (short)h; fl[j] = (short)f2bf(v - bf2f(h));
      }
      B2h[c][s] = fh;
      if (wv == 0) wS[c*2 + s][lane] = fl;
    }
  }
  #pragma unroll
  for (int s = 0; s < 2; ++s) {
    s16x8 fh, fl;
    #pragma unroll
    for (int j = 0; j < 8; ++j) {
      const int k = s*32 + q*8 + j;
      const float v = (m < 3) ? w3[k*3 + m] : 0.f;
      const u16 h = f2bf(v);
      fh[j] = (short)h; fl[j] = (short)f2bf(v - bf2f(h));
    }
    B3h[s] = fh;
    if (wv == 0) wS[8 + s][lane] = fl;
  }
  __syncthreads();   // once, outside the main loop: publish wS to all waves

  u16* const hpl = &hS[wv][0][0];   // hi plane (this wave)
  u16* const lpl = &hS[wv][1][0];   // lo plane (this wave)

  for (int it = 0; it < iters; ++it) {
    const int base = (blockIdx.x * iters + it) << 8;   // 256 points / iteration

    // ---- phase A: per-thread fp32 encode -> bf16 feature row in LDS ----
    {
      const float2 xy = xq[base + tid];
      ((float2*)xyS)[tid] = xy;
      const float xf = xy.x, yf = xy.y;
      u32 er[16];
      // (1) hash levels 12..15: issue all 16 long-latency gathers FIRST
      u32 hv[4][4];
      float2 hv32[4][4];
      #pragma unroll
      for (int l = 12; l < 16; ++l) {
        const int res = RESI[l];
        const u32 ix = (u32)floorf(xf * (float)res);
        const u32 iy = (u32)floorf(yf * (float)res);
        const u32 hy = iy * HPRIME, hy1 = hy + HPRIME;
        const u32 i0 = ( ix       ^ hy ) & TMASK;
        const u32 i1 = ((ix + 1u) ^ hy ) & TMASK;
        const u32 i2 = ( ix       ^ hy1) & TMASK;
        const u32 i3 = ((ix + 1u) ^ hy1) & TMASK;
        if constexpr (PACKED) {
          const u32* t = ctab + (size_t)(l - 8) * TBL;
          hv[l-12][0] = t[i0]; hv[l-12][1] = t[i1];
          hv[l-12][2] = t[i2]; hv[l-12][3] = t[i3];
        } else {
          const float2* t = tab32 + (size_t)l * TBL;
          hv32[l-12][0] = t[i0]; hv32[l-12][1] = t[i1];
          hv32[l-12][2] = t[i2]; hv32[l-12][3] = t[i3];
        }
      }
      // (2) dense levels: 0..7 fp32 (tiny, L1-hot), 8..11 packed bf16 (R13 lesson)
      #pragma unroll
      for (int l = 0; l < 12; ++l) {
        const int res = RESI[l];
        const float px = xf * (float)res, py = yf * (float)res;
        const float fx = floorf(px), fy = floorf(py);
        const float wx = px - fx, wy = py - fy;
        const u32 ix = (u32)fx, iy = (u32)fy;
        const float w00 = (1.f-wx)*(1.f-wy), w10 = wx*(1.f-wy);
        const float w01 = (1.f-wx)*wy,       w11 = wx*wy;
        const u32 st  = (u32)res + 1u;
        const u32 i00 = ix + iy*st;
        float f0, f1;
        if (!PACKED || l < 8) {
          const float2* t = tab32 + (size_t)l * TBL;
          const f32x4a eA = *(const f32x4a*)&t[i00];        // e00 | e10
          const f32x4a eB = *(const f32x4a*)&t[i00 + st];   // e01 | e11
          f0 = eA[0]*w00 + eA[2]*w10 + eB[0]*w01 + eB[2]*w11;
          f1 = eA[1]*w00 + eA[3]*w10 + eB[1]*w01 + eB[3]*w11;
        } else {
          const u32* t = ctab + (size_t)(l - 8) * TBL;
          const u32x2a eA = *(const u32x2a*)&t[i00];        // e00 | e10
          const u32x2a eB = *(const u32x2a*)&t[i00 + st];   // e01 | e11
          f0 = blo(eA[0])*w00 + blo(eA[1])*w10 + blo(eB[0])*w01 + blo(eB[1])*w11;
          f1 = bhi(eA[0])*w00 + bhi(eA[1])*w10 + bhi(eB[0])*w01 + bhi(eB[1])*w11;
        }
        er[l] = cvtpk(f0, f1);
      }
      // (3) consume hash gathers
      #pragma unroll
      for (int hl = 0; hl < 4; ++hl) {
        const int res = RESI[12 + hl];
        const float px = xf * (float)res, py = yf * (float)res;
        const float wx = px - floorf(px), wy = py - floorf(py);
        const float w00 = (1.f-wx)*(1.f-wy), w10 = wx*(1.f-wy);
        const float w01 = (1.f-wx)*wy,       w11 = wx*wy;
        float f0, f1;
        if constexpr (PACKED) {
          f0 = blo(hv[hl][0])*w00 + blo(hv[hl][1])*w10
             + blo(hv[hl][2])*w01 + blo(hv[hl][3])*w11;
          f1 = bhi(hv[hl][0])*w00 + bhi(hv[hl][1])*w10
             + bhi(hv[hl][2])*w01 + bhi(hv[hl][3])*w11;
        } else {
          f0 = hv32[hl][0].x*w00 + hv32[hl][1].x*w10 + hv32[hl][2].x*w01 + hv32[hl][3].x*w11;
          f1 = hv32[hl][0].y*w00 + hv32[hl][1].y*w10 + hv32[hl][2].y*w01 + hv32[hl][3].y*w11;
        }
        er[12 + hl] = cvtpk(f0, f1);
      }
      uint4* rowp = (uint4*)&encS[tid * 40];
      rowp[0] = make_uint4(er[0],  er[1],  er[2],  er[3]);
      rowp[1] = make_uint4(er[4],  er[5],  er[6],  er[7]);
      rowp[2] = make_uint4(er[8],  er[9],  er[10], er[11]);
      rowp[3] = make_uint4(er[12], er[13], er[14], er[15]);
    }

    // ---- phase B: per-wave MFMA MLP, 4 tiles of 16 points (wave-private, no barriers) ----
    #pragma unroll 1
    for (int t4 = 0; t4 < 4; ++t4) {
      const int rbase = wv*64 + t4*16;
      const s16x8 a1 = *(const s16x8*)&encS[(rbase + m)*40 + q*8];

      float xr[4], yr[4];
      #pragma unroll
      for (int r = 0; r < 4; ++r) {
        const float2 v = ((const float2*)xyS)[rbase + q*4 + r];
        xr[r] = v.x; yr[r] = v.y;
      }

      f32x4 acc[4];
      #pragma unroll
      for (int c = 0; c < 4; ++c) {
        f32x4 z;
        #pragma unroll
        for (int r = 0; r < 4; ++r) z[r] = xr[r]*w1x[c] + yr[r]*w1y[c];  // fp32 x,y path
        acc[c] = MFMA(a1, B1[c], z);
      }

      // relu + hi/lo bf16 split -> u16 planes, stride 72 (write banks 16-spread, ~free)
      #pragma unroll
      for (int c = 0; c < 4; ++c)
        #pragma unroll
        for (int r = 0; r < 4; ++r) {
          const float h = fmaxf(acc[c][r], 0.f);
          const u32 hp_ = cvtpk(h, h);                                  // lo16 = bf16(h)
          const float lf = h - __builtin_bit_cast(float, hp_ << 16);
          const u32 lp_ = cvtpk(lf, lf);
          const int idx = (q*4 + r)*72 + c*16 + m;
          hpl[idx] = (u16)hp_;
          lpl[idx] = (u16)lp_;
        }

      s16x8 hi0 = *(const s16x8*)&hpl[m*72 + q*8];
      s16x8 hi1 = *(const s16x8*)&hpl[m*72 + 32 + q*8];
      s16x8 lo0 = *(const s16x8*)&lpl[m*72 + q*8];
      s16x8 lo1 = *(const s16x8*)&lpl[m*72 + 32 + q*8];

      #pragma unroll
      for (int c = 0; c < 4; ++c) {
        const s16x8 b2l0 = wS[c*2 + 0][lane];   // cold lo-frags from shared LDS
        const s16x8 b2l1 = wS[c*2 + 1][lane];
        f32x4 z = {0.f,0.f,0.f,0.f};
        z = MFMA(hi0, B2h[c][0], z); z = MFMA(hi1, B2h[c][1], z);
        z = MFMA(lo0, B2h[c][0], z); z = MFMA(lo1, B2h[c][1], z);
        z = MFMA(hi0, b2l0,      z); z = MFMA(hi1, b2l1,      z);
        acc[c] = z;
      }

      #pragma unroll
      for (int c = 0; c < 4; ++c)
        #pragma unroll
        for (int r = 0; r < 4; ++r) {
          const float h = fmaxf(acc[c][r], 0.f);
          const u32 hp_ = cvtpk(h, h);
          const float lf = h - __builtin_bit_cast(float, hp_ << 16);
          const u32 lp_ = cvtpk(lf, lf);
          const int idx = (q*4 + r)*72 + c*16 + m;
          hpl[idx] = (u16)hp_;
          lpl[idx] = (u16)lp_;
        }

      hi0 = *(const s16x8*)&hpl[m*72 + q*8];
      hi1 = *(const s16x8*)&hpl[m*72 + 32 + q*8];
      lo0 = *(const s16x8*)&lpl[m*72 + q*8];
      lo1 = *(const s16x8*)&lpl[m*72 + 32 + q*8];

      const s16x8 b3l0 = wS[8][lane];
      const s16x8 b3l1 = wS[9][lane];
      f32x4 z = {0.f,0.f,0.f,0.f};
      z = MFMA(hi0, B3h[0], z); z = MFMA(hi1, B3h[1], z);
      z = MFMA(lo0, B3h[0], z); z = MFMA(lo1, B3h[1], z);
      z = MFMA(hi0, b3l0,   z); z = MFMA(hi1, b3l1,   z);

      if (m < 3) {   // C: row = q*4+r, col = m
        #pragma unroll
        for (int r = 0; r < 4; ++r) {
          const int pi = base + rbase + q*4 + r;
          const size_t oi = SORT ? (size_t)perm[pi] : (size_t)pi;
          out[oi*3 + m] = z[r];
        }
      }
    }
  }
}

extern "C" void kernel_launch(void* const* d_in, const int* in_sizes, int n_in,
                              void* d_out, int out_size, void* d_ws, size_t ws_size,
                              hipStream_t stream) {
  const int N = in_sizes[0] / 2;            // 2^21 points
  const int ITERS = 4;
  const int blocks = N / (256 * ITERS);     // 2048 blocks
  // workspace layout (56.06 MiB total; ws >= 56.25 MiB proven in R12)
  const size_t ctab_b   = (size_t)8 * TBL * 4;             // 16 MB packed levels 8..15
  const size_t xs_off   = ctab_b;                          // sorted points, 16 MB
  const size_t perm_off = xs_off + (size_t)N * 8;          // perm, 8 MB
  const size_t bh_off   = perm_off + (size_t)N * 4;        // per-block histograms, 16 MB
  const size_t tot_off  = bh_off + (size_t)NBLK * NBINS * 4;
  const size_t need     = tot_off + (size_t)NBINS * 4;     // + 64 KB

  char* ws = (char*)d_ws;
  if (ws_size >= need && (N % NBLK) == 0) {
    const int ppb = N / NBLK;
    // level-8 entries start at float2 index 8*TBL = float4 index 4*TBL; 8 levels = 4*TBL float4
    cvt_tab<<<2048, 256, 0, stream>>>(((const float4*)d_in[1]) + (size_t)4*TBL,
                                      (uint2*)d_ws, (int)(4*TBL));
    u32* bh    = (u32*)(ws + bh_off);
    u32* tot   = (u32*)(ws + tot_off);
    float2* xs = (float2*)(ws + xs_off);
    u32* perm  = (u32*)(ws + perm_off);
    histb_k<<<NBLK, 256, 0, stream>>>((const float2*)d_in[0], bh, ppb);
    scanb_k<<<NBINS/256, 256, 0, stream>>>(bh, tot);
    scant_k<<<1, 1024, 0, stream>>>(tot);
    scatb_k<<<NBLK, 256, 0, stream>>>((const float2*)d_in[0], bh, tot, xs, perm, ppb);
    ngp_fused<true, true><<<blocks, 256, 0, stream>>>(
        xs, (const float2*)d_in[1], (const u32*)d_ws, perm,
        (const float*)d_in[2], (const float*)d_in[3], (const float*)d_in[4],
        (float*)d_out, ITERS);
  } else if (ws_size >= ctab_b) {
    cvt_tab<<<2048, 256, 0, stream>>>(((const float4*)d_in[1]) + (size_t)4*TBL,
                                      (uint2*)d_ws, (int)(4*TBL));
    ngp_fused<true, false><<<blocks, 256, 0, stream>>>(
        (const float2*)d_in[0], (const float2*)d_in[1], (const u32*)d_ws, nullptr,
        (const float*)d_in[2], (const float*)d_in[3], (const float*)d_in[4],
        (float*)d_out, ITERS);
  } else {
    ngp_fused<false, false><<<blocks, 256, 0, stream>>>(
        (const float2*)d_in[0], (const float2*)d_in[1], (const u32*)d_ws, nullptr,
        (const float*)d_in[2], (const float*)d_in[3], (const float*)d_in[4],
        (float*)d_out, ITERS);
  }
}

// Round 9
// 371.788 us; speedup vs baseline: 1.4390x; 1.0142x over previous
//
#include <hip/hip_runtime.h>

typedef unsigned int u32;
typedef unsigned short u16;
typedef __attribute__((ext_vector_type(8))) short s16x8;
typedef __attribute__((ext_vector_type(4))) float f32x4;
typedef float f32x4a __attribute__((ext_vector_type(4), aligned(8)));  // 8B-aligned 16B load
typedef u32  u32x2a  __attribute__((ext_vector_type(2), aligned(4)));  // 4B-aligned 8B load

#define TBL    524288u
#define TMASK  (TBL - 1u)
#define HPRIME 2654435761u
#define NBINS  16384            // 128 x 128 Morton bins (~128 pts/bin)
#define NBLK   256              // sort blocks = 16 groups x 16; ppb = 8192
#define NGRP   16
#define GSZ    16

// res[l] = floor(16 * 1.3819^l); dense (linear) while (res+1)^2 <= 2^19 -> levels 0..11
__device__ constexpr int RESI[16] = {16,22,30,42,58,80,111,153,212,294,406,561,775,1072,1481,2047};

static __device__ __forceinline__ u16 f2bf(float f){            // RNE f32->bf16 (manual)
  u32 u = __builtin_bit_cast(u32, f);
  return (u16)((u + 0x7fffu + ((u >> 16) & 1u)) >> 16);
}
static __device__ __forceinline__ float bf2f(u16 h){ return __builtin_bit_cast(float, (u32)h << 16); }
static __device__ __forceinline__ float blo(u32 e){ return __builtin_bit_cast(float, (u32)(e << 16)); }
static __device__ __forceinline__ float bhi(u32 e){ return __builtin_bit_cast(float, (u32)(e & 0xffff0000u)); }
static __device__ __forceinline__ u32 packbf2(float a, float b){ return (u32)f2bf(a) | ((u32)f2bf(b) << 16); }
// HW packed RNE f32->bf16 (gfx950): D.lo = bf16(a), D.hi = bf16(b). Same rounding as f2bf.
static __device__ __forceinline__ u32 cvtpk(float a, float b){
  u32 r; asm("v_cvt_pk_bf16_f32 %0, %1, %2" : "=v"(r) : "v"(a), "v"(b)); return r;
}
static __device__ __forceinline__ u32 spread8(u32 v){
  v &= 0xFFu;
  v = (v | (v << 4)) & 0x0F0Fu;
  v = (v | (v << 2)) & 0x3333u;
  v = (v | (v << 1)) & 0x5555u;
  return v;
}
// 14-bit Morton key: 7 bits x, 7 bits y (128x128) -> key < 16384
static __device__ __forceinline__ u32 mkey(float x, float y){
  u32 kx = (u32)(x * 128.f); kx = kx > 127u ? 127u : kx;
  u32 ky = (u32)(y * 128.f); ky = ky > 127u ? 127u : ky;
  return spread8(kx) | (spread8(ky) << 1);
}

#define MFMA(A,B,C) __builtin_amdgcn_mfma_f32_16x16x32_bf16((A),(B),(C),0,0,0)

// Pre-pass: pack levels 8..15 to bf16 (16 MB). Levels 0..7 (~330 KB fp32) are L1-hot as fp32.
__global__ __launch_bounds__(256) void cvt_tab(const float4* __restrict__ src,
                                               uint2* __restrict__ dst, int n4) {
  for (int i = blockIdx.x*256 + threadIdx.x; i < n4; i += gridDim.x*256) {
    const float4 v = src[i];
    dst[i] = make_uint2(packbf2(v.x, v.y), packbf2(v.z, v.w));
  }
}

// ---------------- R15 Morton counting sort (all scans depth<=16, no dependent-load chains) ----
// R14's scanb was a 256-deep DEPENDENT load chain per thread (~500cy each) -> ~90us alone.
// R15: bh is u16 (counts<=8192; within-bin prefixes ~<=200 for uniform input); scan split
// into P1 (group sums), P2 (scan 16 groups/bin), scant (bin starts), P3 (in-group prefix).
__global__ __launch_bounds__(256) void histb_k(const float2* __restrict__ xq,
                                               u16* __restrict__ bh, int ppb) {
  __shared__ u32 cnt[NBINS];                       // 64 KB
  const int j = blockIdx.x;
  for (int i = threadIdx.x; i < NBINS; i += 256) cnt[i] = 0;
  __syncthreads();
  const float2* p = xq + (size_t)j * ppb;
  for (int i = threadIdx.x; i < ppb; i += 256) {
    const float2 v = p[i];
    atomicAdd(&cnt[mkey(v.x, v.y)], 1u);           // LDS atomic (CU-local)
  }
  __syncthreads();
  u16* o = bh + (size_t)j * NBINS;
  for (int i = threadIdx.x; i < NBINS; i += 256) o[i] = (u16)cnt[i];
}
// P1: gs[g][b] = sum over the group's 16 blocks (16 INDEPENDENT loads -> pipelined)
__global__ __launch_bounds__(256) void scang1_k(const u16* __restrict__ bh,
                                                u32* __restrict__ gs) {
  const int t = blockIdx.x*256 + threadIdx.x;      // t < NGRP*NBINS
  const int g = t / NBINS, b = t % NBINS;
  u32 s = 0;
  #pragma unroll
  for (int k = 0; k < GSZ; ++k) s += bh[(size_t)(g*GSZ + k)*NBINS + b];
  gs[t] = s;
}
// P2: per-bin exclusive scan over 16 group sums; tot[b] = bin total
__global__ __launch_bounds__(256) void scang2_k(u32* __restrict__ gs, u32* __restrict__ tot) {
  const int b = blockIdx.x*256 + threadIdx.x;      // b < NBINS
  u32 run = 0;
  #pragma unroll
  for (int g = 0; g < NGRP; ++g) {
    const size_t k = (size_t)g*NBINS + b;
    const u32 v = gs[k]; gs[k] = run; run += v;
  }
  tot[b] = run;
}
// single-block exclusive scan of the 16384 bin totals -> bin start offsets (in place)
__global__ __launch_bounds__(1024) void scant_k(u32* __restrict__ tot) {
  __shared__ u32 part[1024];
  const int t = threadIdx.x;
  u32 loc[16]; u32 s = 0;
  #pragma unroll
  for (int i = 0; i < 16; ++i) { loc[i] = tot[t*16 + i]; s += loc[i]; }
  part[t] = s;
  __syncthreads();
  for (int d = 1; d < 1024; d <<= 1) {
    const u32 v = (t >= d) ? part[t - d] : 0u;
    __syncthreads();
    part[t] += v;
    __syncthreads();
  }
  u32 run = part[t] - s;                           // exclusive prefix of this thread's chunk
  #pragma unroll
  for (int i = 0; i < 16; ++i) { tot[t*16 + i] = run; run += loc[i]; }
}
// P3: within-group exclusive prefix + group base -> bh[j][b] = within-bin offset of block j
__global__ __launch_bounds__(256) void scang3_k(u16* __restrict__ bh,
                                                const u32* __restrict__ gs) {
  const int t = blockIdx.x*256 + threadIdx.x;
  const int g = t / NBINS, b = t % NBINS;
  u32 run = gs[t];                                 // exclusive group base within bin
  #pragma unroll
  for (int k = 0; k < GSZ; ++k) {
    const size_t idx = (size_t)(g*GSZ + k)*NBINS + b;
    const u32 v = bh[idx]; bh[idx] = (u16)run; run += v;
  }
}
__global__ __launch_bounds__(256) void scatb_k(const float2* __restrict__ xq,
                                               const u16* __restrict__ bh,
                                               const u32* __restrict__ binst,
                                               float2* __restrict__ xs,
                                               u32* __restrict__ perm, int ppb) {
  __shared__ u32 offs[NBINS];                      // this block's global write cursors, 64 KB
  const int j = blockIdx.x;
  for (int i = threadIdx.x; i < NBINS; i += 256)
    offs[i] = (u32)bh[(size_t)j * NBINS + i] + binst[i];
  __syncthreads();
  const size_t base = (size_t)j * ppb;
  for (int i = threadIdx.x; i < ppb; i += 256) {
    const float2 pt = xq[base + i];
    const u32 pos = atomicAdd(&offs[mkey(pt.x, pt.y)], 1u);   // LDS atomic-return
    xs[pos] = pt;
    perm[pos] = (u32)(base + i);
  }
}

// Fused instant-NGP: fp32 hash-grid encode (per-thread) + 34->64->64->3 MLP via bf16-split MFMA.
// OCCUPANCY MODEL (verified R8/R9/R10): 3 blocks/CU iff arch VGPR <= ~104 AND LDS <= 53248 B.
// History: 515(R2)->443(R5)->392(R6)->375(R8)->363(R10)->336(R11)->176/535(R12 sort)
// ->197/402(R13)->195/377(R14). R15: XCD-contiguous swizzle (each XCD gets one contiguous
// Morton band -> per-XCD L2 hot set ~1/8 of tables, fits 4MB) + depth-16 scan pre-passes.
template<bool PACKED, bool SORT>
__global__ __launch_bounds__(256, 2) void ngp_fused(
    const float2* __restrict__ xq,    // [N] (x,y) fp32 (sorted when SORT)
    const float2* __restrict__ tab32, // [16*2^19] (f0,f1) fp32
    const u32*    __restrict__ ctab,  // [8*2^19] packed bf16 pair, levels 8..15 (d_ws)
    const u32*    __restrict__ perm,  // [N] sorted-pos -> original index (SORT path)
    const float*  __restrict__ w1,    // [34][64]
    const float*  __restrict__ w2,    // [64][64]
    const float*  __restrict__ w3,    // [64][3]
    float* __restrict__ out,          // [N][3]
    int iters)
{
  __shared__ __align__(16) u16   encS[256 * 40];   // 32 bf16 features + 8 pad (80 B stride)
  __shared__ __align__(16) float xyS [256 * 2];    // fp32 x,y per point
  __shared__ __align__(16) u16   hS  [4][2][16*72];// [wave][hi/lo plane][row*72 + col]
  __shared__ __align__(16) s16x8 wS  [10][64];     // shared lo-frags: B2l[c][s]->c*2+s, B3l[s]->8+s

  const int tid  = threadIdx.x;
  const int lane = tid & 63;
  const int wv   = tid >> 6;
  const int m    = lane & 15;   // A row / B,C col
  const int q    = lane >> 4;   // k-quad

  // XCD-contiguous work swizzle: HW assigns blockIdx round-robin to the 8 XCDs; remap so
  // XCD x processes one contiguous Morton band (grid 2048 = 8 x 256, bijective).
  const int wb = ((blockIdx.x & 7) * (int)(gridDim.x >> 3)) + (blockIdx.x >> 3);

  // ---- build B-frags from global fp32 weights (one-time; L2-cached) ----
  float w1x[4], w1y[4];
  s16x8 B1[4], B2h[4][2], B3h[2];
  #pragma unroll
  for (int c = 0; c < 4; ++c) {
    const int n = c*16 + m;
    w1x[c] = w1[n]; w1y[c] = w1[64 + n];
    s16x8 f1;
    #pragma unroll
    for (int j = 0; j < 8; ++j) {               // B1: feature rows 2..33, K=32 exactly
      const int k = q*8 + j;
      f1[j] = (short)f2bf(w1[(2 + k)*64 + n]);
    }
    B1[c] = f1;
    #pragma unroll
    for (int s = 0; s < 2; ++s) {
      s16x8 fh, fl;
      #pragma unroll
      for (int j = 0; j < 8; ++j) {
        const int k = s*32 + q*8 + j;
        const float v = w2[k*64 + n];
        const u16 h = f2bf(v);
        fh[j] = (short)h; fl[j] = (short)f2bf(v - bf2f(h));
      }
      B2h[c][s] = fh;
      if (wv == 0) wS[c*2 + s][lane] = fl;
    }
  }
  #pragma unroll
  for (int s = 0; s < 2; ++s) {
    s16x8 fh, fl;
    #pragma unroll
    for (int j = 0; j < 8; ++j) {
      const int k = s*32 + q*8 + j;
      const float v = (m < 3) ? w3[k*3 + m] : 0.f;
      const u16 h = f2bf(v);
      fh[j] = (short)h; fl[j] = (short)f2bf(v - bf2f(h));
    }
    B3h[s] = fh;
    if (wv == 0) wS[8 + s][lane] = fl;
  }
  __syncthreads();   // once, outside the main loop: publish wS to all waves

  u16* const hpl = &hS[wv][0][0];   // hi plane (this wave)
  u16* const lpl = &hS[wv][1][0];   // lo plane (this wave)

  for (int it = 0; it < iters; ++it) {
    const int base = (wb * iters + it) << 8;           // 256 points / iteration

    // ---- phase A: per-thread fp32 encode -> bf16 feature row in LDS ----
    {
      const float2 xy = xq[base + tid];
      ((float2*)xyS)[tid] = xy;
      const float xf = xy.x, yf = xy.y;
      u32 er[16];
      // (1) hash levels 12..15: issue all 16 long-latency gathers FIRST
      u32 hv[4][4];
      float2 hv32[4][4];
      #pragma unroll
      for (int l = 12; l < 16; ++l) {
        const int res = RESI[l];
        const u32 ix = (u32)floorf(xf * (float)res);
        const u32 iy = (u32)floorf(yf * (float)res);
        const u32 hy = iy * HPRIME, hy1 = hy + HPRIME;
        const u32 i0 = ( ix       ^ hy ) & TMASK;
        const u32 i1 = ((ix + 1u) ^ hy ) & TMASK;
        const u32 i2 = ( ix       ^ hy1) & TMASK;
        const u32 i3 = ((ix + 1u) ^ hy1) & TMASK;
        if constexpr (PACKED) {
          const u32* t = ctab + (size_t)(l - 8) * TBL;
          hv[l-12][0] = t[i0]; hv[l-12][1] = t[i1];
          hv[l-12][2] = t[i2]; hv[l-12][3] = t[i3];
        } else {
          const float2* t = tab32 + (size_t)l * TBL;
          hv32[l-12][0] = t[i0]; hv32[l-12][1] = t[i1];
          hv32[l-12][2] = t[i2]; hv32[l-12][3] = t[i3];
        }
      }
      // (2) dense levels: 0..7 fp32 (tiny, L1-hot), 8..11 packed bf16 (R13 lesson)
      #pragma unroll
      for (int l = 0; l < 12; ++l) {
        const int res = RESI[l];
        const float px = xf * (float)res, py = yf * (float)res;
        const float fx = floorf(px), fy = floorf(py);
        const float wx = px - fx, wy = py - fy;
        const u32 ix = (u32)fx, iy = (u32)fy;
        const float w00 = (1.f-wx)*(1.f-wy), w10 = wx*(1.f-wy);
        const float w01 = (1.f-wx)*wy,       w11 = wx*wy;
        const u32 st  = (u32)res + 1u;
        const u32 i00 = ix + iy*st;
        float f0, f1;
        if (!PACKED || l < 8) {
          const float2* t = tab32 + (size_t)l * TBL;
          const f32x4a eA = *(const f32x4a*)&t[i00];        // e00 | e10
          const f32x4a eB = *(const f32x4a*)&t[i00 + st];   // e01 | e11
          f0 = eA[0]*w00 + eA[2]*w10 + eB[0]*w01 + eB[2]*w11;
          f1 = eA[1]*w00 + eA[3]*w10 + eB[1]*w01 + eB[3]*w11;
        } else {
          const u32* t = ctab + (size_t)(l - 8) * TBL;
          const u32x2a eA = *(const u32x2a*)&t[i00];        // e00 | e10
          const u32x2a eB = *(const u32x2a*)&t[i00 + st];   // e01 | e11
          f0 = blo(eA[0])*w00 + blo(eA[1])*w10 + blo(eB[0])*w01 + blo(eB[1])*w11;
          f1 = bhi(eA[0])*w00 + bhi(eA[1])*w10 + bhi(eB[0])*w01 + bhi(eB[1])*w11;
        }
        er[l] = cvtpk(f0, f1);
      }
      // (3) consume hash gathers
      #pragma unroll
      for (int hl = 0; hl < 4; ++hl) {
        const int res = RESI[12 + hl];
        const float px = xf * (float)res, py = yf * (float)res;
        const float wx = px - floorf(px), wy = py - floorf(py);
        const float w00 = (1.f-wx)*(1.f-wy), w10 = wx*(1.f-wy);
        const float w01 = (1.f-wx)*wy,       w11 = wx*wy;
        float f0, f1;
        if constexpr (PACKED) {
          f0 = blo(hv[hl][0])*w00 + blo(hv[hl][1])*w10
             + blo(hv[hl][2])*w01 + blo(hv[hl][3])*w11;
          f1 = bhi(hv[hl][0])*w00 + bhi(hv[hl][1])*w10
             + bhi(hv[hl][2])*w01 + bhi(hv[hl][3])*w11;
        } else {
          f0 = hv32[hl][0].x*w00 + hv32[hl][1].x*w10 + hv32[hl][2].x*w01 + hv32[hl][3].x*w11;
          f1 = hv32[hl][0].y*w00 + hv32[hl][1].y*w10 + hv32[hl][2].y*w01 + hv32[hl][3].y*w11;
        }
        er[12 + hl] = cvtpk(f0, f1);
      }
      uint4* rowp = (uint4*)&encS[tid * 40];
      rowp[0] = make_uint4(er[0],  er[1],  er[2],  er[3]);
      rowp[1] = make_uint4(er[4],  er[5],  er[6],  er[7]);
      rowp[2] = make_uint4(er[8],  er[9],  er[10], er[11]);
      rowp[3] = make_uint4(er[12], er[13], er[14], er[15]);
    }

    // ---- phase B: per-wave MFMA MLP, 4 tiles of 16 points (wave-private, no barriers) ----
    #pragma unroll 1
    for (int t4 = 0; t4 < 4; ++t4) {
      const int rbase = wv*64 + t4*16;
      const s16x8 a1 = *(const s16x8*)&encS[(rbase + m)*40 + q*8];

      float xr[4], yr[4];
      #pragma unroll
      for (int r = 0; r < 4; ++r) {
        const float2 v = ((const float2*)xyS)[rbase + q*4 + r];
        xr[r] = v.x; yr[r] = v.y;
      }

      f32x4 acc[4];
      #pragma unroll
      for (int c = 0; c < 4; ++c) {
        f32x4 z;
        #pragma unroll
        for (int r = 0; r < 4; ++r) z[r] = xr[r]*w1x[c] + yr[r]*w1y[c];  // fp32 x,y path
        acc[c] = MFMA(a1, B1[c], z);
      }

      // relu + hi/lo bf16 split -> u16 planes, stride 72 (write banks 16-spread, ~free)
      #pragma unroll
      for (int c = 0; c < 4; ++c)
        #pragma unroll
        for (int r = 0; r < 4; ++r) {
          const float h = fmaxf(acc[c][r], 0.f);
          const u32 hp_ = cvtpk(h, h);                                  // lo16 = bf16(h)
          const float lf = h - __builtin_bit_cast(float, hp_ << 16);
          const u32 lp_ = cvtpk(lf, lf);
          const int idx = (q*4 + r)*72 + c*16 + m;
          hpl[idx] = (u16)hp_;
          lpl[idx] = (u16)lp_;
        }

      s16x8 hi0 = *(const s16x8*)&hpl[m*72 + q*8];
      s16x8 hi1 = *(const s16x8*)&hpl[m*72 + 32 + q*8];
      s16x8 lo0 = *(const s16x8*)&lpl[m*72 + q*8];
      s16x8 lo1 = *(const s16x8*)&lpl[m*72 + 32 + q*8];

      #pragma unroll
      for (int c = 0; c < 4; ++c) {
        const s16x8 b2l0 = wS[c*2 + 0][lane];   // cold lo-frags from shared LDS
        const s16x8 b2l1 = wS[c*2 + 1][lane];
        f32x4 z = {0.f,0.f,0.f,0.f};
        z = MFMA(hi0, B2h[c][0], z); z = MFMA(hi1, B2h[c][1], z);
        z = MFMA(lo0, B2h[c][0], z); z = MFMA(lo1, B2h[c][1], z);
        z = MFMA(hi0, b2l0,      z); z = MFMA(hi1, b2l1,      z);
        acc[c] = z;
      }

      #pragma unroll
      for (int c = 0; c < 4; ++c)
        #pragma unroll
        for (int r = 0; r < 4; ++r) {
          const float h = fmaxf(acc[c][r], 0.f);
          const u32 hp_ = cvtpk(h, h);
          const float lf = h - __builtin_bit_cast(float, hp_ << 16);
          const u32 lp_ = cvtpk(lf, lf);
          const int idx = (q*4 + r)*72 + c*16 + m;
          hpl[idx] = (u16)hp_;
          lpl[idx] = (u16)lp_;
        }

      hi0 = *(const s16x8*)&hpl[m*72 + q*8];
      hi1 = *(const s16x8*)&hpl[m*72 + 32 + q*8];
      lo0 = *(const s16x8*)&lpl[m*72 + q*8];
      lo1 = *(const s16x8*)&lpl[m*72 + 32 + q*8];

      const s16x8 b3l0 = wS[8][lane];
      const s16x8 b3l1 = wS[9][lane];
      f32x4 z = {0.f,0.f,0.f,0.f};
      z = MFMA(hi0, B3h[0], z); z = MFMA(hi1, B3h[1], z);
      z = MFMA(lo0, B3h[0], z); z = MFMA(lo1, B3h[1], z);
      z = MFMA(hi0, b3l0,   z); z = MFMA(hi1, b3l1,   z);

      if (m < 3) {   // C: row = q*4+r, col = m
        #pragma unroll
        for (int r = 0; r < 4; ++r) {
          const int pi = base + rbase + q*4 + r;
          const size_t oi = SORT ? (size_t)perm[pi] : (size_t)pi;
          out[oi*3 + m] = z[r];
        }
      }
    }
  }
}

extern "C" void kernel_launch(void* const* d_in, const int* in_sizes, int n_in,
                              void* d_out, int out_size, void* d_ws, size_t ws_size,
                              hipStream_t stream) {
  const int N = in_sizes[0] / 2;            // 2^21 points
  const int ITERS = 4;
  const int blocks = N / (256 * ITERS);     // 2048 blocks
  // workspace layout (49.07 MiB total; ws >= 56.06 MiB proven in R14)
  const size_t ctab_b   = (size_t)8 * TBL * 4;             // 16 MB packed levels 8..15
  const size_t xs_off   = ctab_b;                          // sorted points, 16 MB
  const size_t perm_off = xs_off + (size_t)N * 8;          // perm, 8 MB
  const size_t bh_off   = perm_off + (size_t)N * 4;        // per-block histograms u16, 8 MB
  const size_t gs_off   = bh_off + (size_t)NBLK * NBINS * 2;  // group sums, 1 MB
  const size_t tot_off  = gs_off + (size_t)NGRP * NBINS * 4;
  const size_t need     = tot_off + (size_t)NBINS * 4;     // + 64 KB

  char* ws = (char*)d_ws;
  if (ws_size >= need && (N % NBLK) == 0 && (blocks % 8) == 0) {
    const int ppb = N / NBLK;
    // level-8 entries start at float2 index 8*TBL = float4 index 4*TBL; 8 levels = 4*TBL float4
    cvt_tab<<<2048, 256, 0, stream>>>(((const float4*)d_in[1]) + (size_t)4*TBL,
                                      (uint2*)d_ws, (int)(4*TBL));
    u16* bh    = (u16*)(ws + bh_off);
    u32* gs    = (u32*)(ws + gs_off);
    u32* tot   = (u32*)(ws + tot_off);
    float2* xs = (float2*)(ws + xs_off);
    u32* perm  = (u32*)(ws + perm_off);
    histb_k<<<NBLK, 256, 0, stream>>>((const float2*)d_in[0], bh, ppb);
    scang1_k<<<NGRP*NBINS/256, 256, 0, stream>>>(bh, gs);
    scang2_k<<<NBINS/256, 256, 0, stream>>>(gs, tot);
    scant_k<<<1, 1024, 0, stream>>>(tot);
    scang3_k<<<NGRP*NBINS/256, 256, 0, stream>>>(bh, gs);
    scatb_k<<<NBLK, 256, 0, stream>>>((const float2*)d_in[0], bh, tot, xs, perm, ppb);
    ngp_fused<true, true><<<blocks, 256, 0, stream>>>(
        xs, (const float2*)d_in[1], (const u32*)d_ws, perm,
        (const float*)d_in[2], (const float*)d_in[3], (const float*)d_in[4],
        (float*)d_out, ITERS);
  } else if (ws_size >= ctab_b) {
    cvt_tab<<<2048, 256, 0, stream>>>(((const float4*)d_in[1]) + (size_t)4*TBL,
                                      (uint2*)d_ws, (int)(4*TBL));
    ngp_fused<true, false><<<blocks, 256, 0, stream>>>(
        (const float2*)d_in[0], (const float2*)d_in[1], (const u32*)d_ws, nullptr,
        (const float*)d_in[2], (const float*)d_in[3], (const float*)d_in[4],
        (float*)d_out, ITERS);
  } else {
    ngp_fused<false, false><<<blocks, 256, 0, stream>>>(
        (const float2*)d_in[0], (const float2*)d_in[1], (const u32*)d_ws, nullptr,
        (const float*)d_in[2], (const float*)d_in[3], (const float*)d_in[4],
        (float*)d_out, ITERS);
  }
}